// Round 5
// baseline (24247.202 us; speedup 1.0000x reference)
//
#include <hip/hip_runtime.h>
#include <stdint.h>

// LWTA MLP, decision/value-split + latency-pipelined sparse GEMMs.
//   k1a: dense fp32 GEMM (reg-prefetch) -> winner idx + uncertainty flags
//   k1b: fp64 winner-value recompute (1/16 FLOPs)
//   k1c: fp64 exact resolve of flagged L1 blocks
//   k2a: sparse fp32 GEMM, single-barrier double-buffered LDS, reg metadata
//   k2b: fp64 resolve of flagged L2 blocks
//   k3 : sparse fp32 GEMM -> dense out
// Metadata arrays are TRANSPOSED [kblock][8192] so sparse GEMMs fetch
// per-row metadata as broadcast float4/uint2 loads one tile ahead.

#define EPS1 3.0e-4f
#define EPS2 5.0e-5f
#define MST  8192L   // metadata row stride (batch size)

// ---------------------------------------------------------------------------
// k1a: dense fp32 GEMM, 128x256 tile, BK=32, reg-prefetch pipeline.
__global__ __launch_bounds__(256, 2)
void k1a_dense_f32_flags(const float* __restrict__ A, const float* __restrict__ Bw,
                         const float* __restrict__ bias, int K,
                         uint8_t* __restrict__ iOut, uint8_t* __restrict__ fOut)
{
    __shared__ float As[32 * 132];
    __shared__ float Bs[32 * 260];
    const int t = threadIdx.x, tx = t & 15, ty = t >> 4;
    const long m0 = (long)blockIdx.y * 128, n0 = (long)blockIdx.x * 256;

    float acc[8][4][4];
#pragma unroll
    for (int r = 0; r < 8; ++r)
#pragma unroll
        for (int g = 0; g < 4; ++g)
#pragma unroll
            for (int d = 0; d < 4; ++d) acc[r][g][d] = 0.f;

    const float* bsrc[8]; int bdst[8];
#pragma unroll
    for (int i = 0; i < 8; ++i) {
        const int f = i * 256 + t, col = f >> 3, kq = (f & 7) * 4;
        bsrc[i] = &Bw[(n0 + col) * (long)K + kq];
        bdst[i] = kq * 260 + col;
    }
    const float* asrc[4]; int adst[4];
#pragma unroll
    for (int i = 0; i < 4; ++i) {
        const int f = i * 256 + t, row = f >> 3, kq = (f & 7) * 4;
        asrc[i] = &A[(m0 + row) * (long)K + kq];
        adst[i] = kq * 132 + row;
    }

    float4 br[8], ar[4];
#pragma unroll
    for (int i = 0; i < 8; ++i) br[i] = *(const float4*)(bsrc[i]);
#pragma unroll
    for (int i = 0; i < 4; ++i) ar[i] = *(const float4*)(asrc[i]);
#pragma unroll
    for (int i = 0; i < 8; ++i) {
        Bs[bdst[i] + 0]   = br[i].x; Bs[bdst[i] + 260] = br[i].y;
        Bs[bdst[i] + 520] = br[i].z; Bs[bdst[i] + 780] = br[i].w;
    }
#pragma unroll
    for (int i = 0; i < 4; ++i) {
        As[adst[i] + 0]   = ar[i].x; As[adst[i] + 132] = ar[i].y;
        As[adst[i] + 264] = ar[i].z; As[adst[i] + 396] = ar[i].w;
    }
    __syncthreads();

    const int nkt = K / 32;
    for (int kt = 0; kt < nkt; ++kt) {
        const bool more = (kt + 1 < nkt);
        if (more) {
            const int k0n = (kt + 1) * 32;
#pragma unroll
            for (int i = 0; i < 8; ++i) br[i] = *(const float4*)(bsrc[i] + k0n);
#pragma unroll
            for (int i = 0; i < 4; ++i) ar[i] = *(const float4*)(asrc[i] + k0n);
        }
#pragma unroll
        for (int kk = 0; kk < 32; ++kk) {
            const float4 a0 = *(const float4*)&As[kk * 132 + ty * 8];
            const float4 a1 = *(const float4*)&As[kk * 132 + ty * 8 + 4];
            float4 bb[4];
#pragma unroll
            for (int g = 0; g < 4; ++g)
                bb[g] = *(const float4*)&Bs[kk * 260 + g * 64 + tx * 4];
            const float arr[8] = {a0.x, a0.y, a0.z, a0.w, a1.x, a1.y, a1.z, a1.w};
#pragma unroll
            for (int r = 0; r < 8; ++r)
#pragma unroll
                for (int g = 0; g < 4; ++g) {
                    acc[r][g][0] += arr[r] * bb[g].x;
                    acc[r][g][1] += arr[r] * bb[g].y;
                    acc[r][g][2] += arr[r] * bb[g].z;
                    acc[r][g][3] += arr[r] * bb[g].w;
                }
        }
        __syncthreads();
        if (more) {
#pragma unroll
            for (int i = 0; i < 8; ++i) {
                Bs[bdst[i] + 0]   = br[i].x; Bs[bdst[i] + 260] = br[i].y;
                Bs[bdst[i] + 520] = br[i].z; Bs[bdst[i] + 780] = br[i].w;
            }
#pragma unroll
            for (int i = 0; i < 4; ++i) {
                As[adst[i] + 0]   = ar[i].x; As[adst[i] + 132] = ar[i].y;
                As[adst[i] + 264] = ar[i].z; As[adst[i] + 396] = ar[i].w;
            }
            __syncthreads();
        }
    }

#pragma unroll
    for (int r = 0; r < 8; ++r) {
        const long row = m0 + ty * 8 + r;
#pragma unroll
        for (int g = 0; g < 4; ++g) {
            float v1 = -3.f, v2 = -3.f; int i1v = 0, bHi = 0;
#pragma unroll
            for (int d = 0; d < 4; ++d) {
                const long j = n0 + g * 64 + tx * 4 + d;
                const float pre = acc[r][g][d] + bias[j];
                const float c = fminf(fmaxf(pre, -1.f), 1.f);
                const int li = (tx & 3) * 4 + d;
                if (c > v1) { v2 = v1; v1 = c; i1v = li; }
                else if (c > v2) v2 = c;
                bHi |= (pre > 1.f - EPS1 && pre < 1.f + EPS1) ? 1 : 0;
            }
#pragma unroll
            for (int mk = 1; mk <= 2; mk <<= 1) {
                const float ov1 = __shfl_xor(v1, mk);
                const int   oi1 = __shfl_xor(i1v, mk);
                const float ov2 = __shfl_xor(v2, mk);
                bHi |= __shfl_xor(bHi, mk);
                if (ov1 > v1 || (ov1 == v1 && oi1 < i1v)) {
                    v2 = fmaxf(v1, ov2); v1 = ov1; i1v = oi1;
                } else v2 = fmaxf(v2, ov1);
            }
            if ((tx & 3) == 0) {
                const bool stable = (v1 >= 1.f) && (v2 >= 1.f) && !bHi;
                const int unc = ((v1 - v2 <= EPS1) && !stable) || (v1 <= -1.f + EPS1);
                const long blk = (n0 >> 4) + g * 4 + (tx >> 2);
                iOut[blk * MST + row] = (uint8_t)i1v;
                fOut[blk * MST + row] = (uint8_t)unc;
            }
        }
    }
}

// ---------------------------------------------------------------------------
// k1b: fp64 winner-value recompute, transposed metadata.
__global__ __launch_bounds__(256)
void k1b_winner_f64(const float* __restrict__ A, const float* __restrict__ Bw,
                    const float* __restrict__ bias, int K,
                    const uint8_t* __restrict__ iIn,
                    double* __restrict__ vOutD, float* __restrict__ vOutF)
{
    __shared__ float4 As2[128 * 9];
    __shared__ float4 Bs2[128 * 9];
    const int t = threadIdx.x, w = t & 7, r0 = t >> 3;
    const long m0 = (long)blockIdx.y * 128, n0 = (long)blockIdx.x * 128;

    long tix[4]; int wj[4]; double acc[4] = {0.0, 0.0, 0.0, 0.0};
#pragma unroll
    for (int q = 0; q < 4; ++q) {
        const int row = r0 + 32 * q;
        tix[q] = (long)(blockIdx.x * 8 + w) * MST + (m0 + row);
        wj[q] = w * 16 + (int)iIn[tix[q]];
    }
    for (int k0 = 0; k0 < K; k0 += 32) {
        __syncthreads();
#pragma unroll
        for (int i = 0; i < 4; ++i) {
            const int f = i * 256 + t, rc = f >> 3, kq = f & 7;
            As2[rc * 9 + (kq ^ (rc & 7))] = *(const float4*)&A[(m0 + rc) * (long)K + k0 + kq * 4];
            Bs2[rc * 9 + (kq ^ (rc & 7))] = *(const float4*)&Bw[(n0 + rc) * (long)K + k0 + kq * 4];
        }
        __syncthreads();
#pragma unroll
        for (int q = 0; q < 4; ++q) {
            const int ra = (r0 + 32 * q) * 9, sa = (r0 + 32 * q) & 7;
            const int rb = wj[q] * 9, sb = wj[q] & 7;
            double s = acc[q];
#pragma unroll
            for (int kq = 0; kq < 8; ++kq) {
                const float4 xa = As2[ra + (kq ^ sa)];
                const float4 wb = Bs2[rb + (kq ^ sb)];
                s += (double)xa.x * wb.x + (double)xa.y * wb.y
                   + (double)xa.z * wb.z + (double)xa.w * wb.w;
            }
            acc[q] = s;
        }
    }
#pragma unroll
    for (int q = 0; q < 4; ++q) {
        double v = acc[q] + (double)bias[n0 + wj[q]];
        v = fmin(fmax(v, -1.0), 1.0);
        vOutD[tix[q]] = v;
        vOutF[tix[q]] = (float)v;
    }
}

// ---------------------------------------------------------------------------
// k1c: fp64 resolve of flagged L1 blocks (transposed index space).
__global__ __launch_bounds__(256)
void k1_resolve(const float* __restrict__ A, const float* __restrict__ Bw,
                const float* __restrict__ bias, const uint8_t* __restrict__ fIn,
                uint8_t* __restrict__ iFix, double* __restrict__ vOutD,
                float* __restrict__ vOutF)
{
    const int gtid = blockIdx.x * 256 + threadIdx.x;
    const int wid = gtid >> 6, lane = gtid & 63;
    const long per = (256L * MST) / ((gridDim.x * 256) >> 6);
    const long s0 = (long)wid * per;
    for (long c = 0; c < per; c += 64) {
        unsigned long long mask = __ballot(fIn[s0 + c + lane] != 0);
        while (mask) {
            const int bit = __builtin_ctzll(mask); mask &= mask - 1;
            const long s = s0 + c + bit;
            const int blk = (int)(s >> 13); const long row = s & (MST - 1);
            const float4* xp = (const float4*)&A[row * 1024 + lane * 16];
            const float4 x0 = xp[0], x1 = xp[1], x2 = xp[2], x3 = xp[3];
            double best = -3.0; int bi = 0;
            for (int u = 0; u < 16; ++u) {
                const float4* wp = (const float4*)&Bw[(long)(blk * 16 + u) * 1024 + lane * 16];
                const float4 w0 = wp[0], w1 = wp[1], w2 = wp[2], w3 = wp[3];
                double su = (double)x0.x * w0.x + (double)x0.y * w0.y
                          + (double)x0.z * w0.z + (double)x0.w * w0.w
                          + (double)x1.x * w1.x + (double)x1.y * w1.y
                          + (double)x1.z * w1.z + (double)x1.w * w1.w
                          + (double)x2.x * w2.x + (double)x2.y * w2.y
                          + (double)x2.z * w2.z + (double)x2.w * w2.w
                          + (double)x3.x * w3.x + (double)x3.y * w3.y
                          + (double)x3.z * w3.z + (double)x3.w * w3.w;
#pragma unroll
                for (int off = 32; off; off >>= 1) su += __shfl_xor(su, off);
                const double xu = fmin(fmax(su + (double)bias[blk * 16 + u], -1.0), 1.0);
                if (xu > best) { best = xu; bi = u; }
            }
            if (lane == 0) { iFix[s] = (uint8_t)bi; vOutD[s] = best; vOutF[s] = (float)best; }
        }
    }
}

// ---------------------------------------------------------------------------
// Sparse GEMM v2: single-barrier double-buffered LDS, reg-prefetched B tile
// and metadata (transposed [kblock][M] layout). 128x128 tile, BK=32.
template<bool LWTA_OUT>
__global__ __launch_bounds__(256, 3)
void sparse_gemm_v2(const float* __restrict__ vA, const uint8_t* __restrict__ iA,
                    const float* __restrict__ Bw, const float* __restrict__ bias,
                    int K, float eps,
                    float* __restrict__ vOut, uint8_t* __restrict__ iOut,
                    uint8_t* __restrict__ fOut, float* __restrict__ dOut, int N)
{
    __shared__ float Bs[2][32 * 132];
    const int t = threadIdx.x, tx = t & 15, ty = t >> 4;
    const long m0 = (long)blockIdx.y * 128, n0 = (long)blockIdx.x * 128;
    const int nkt = K / 32;

    float acc[8][2][4];
#pragma unroll
    for (int r = 0; r < 8; ++r)
#pragma unroll
        for (int g = 0; g < 2; ++g)
#pragma unroll
            for (int d = 0; d < 4; ++d) acc[r][g][d] = 0.f;

    const float* bsrc[4]; int bdst[4];
#pragma unroll
    for (int i = 0; i < 4; ++i) {
        const int f = i * 256 + t, col = f >> 3, kq = (f & 7) * 4;
        bsrc[i] = &Bw[(n0 + col) * (long)K + kq];
        bdst[i] = kq * 132 + col;
    }
    const float*   vbase = vA + m0 + ty * 8;
    const uint8_t* ibase = iA + m0 + ty * 8;

    // prologue: tile 0
    float4 br[4];
#pragma unroll
    for (int i = 0; i < 4; ++i) br[i] = *(const float4*)(bsrc[i]);
    float4 va0 = *(const float4*)(vbase);
    float4 va1 = *(const float4*)(vbase + 4);
    float4 vb0 = *(const float4*)(vbase + MST);
    float4 vb1 = *(const float4*)(vbase + MST + 4);
    uint2  ia0 = *(const uint2*)(ibase);
    uint2  ia1 = *(const uint2*)(ibase + MST);
#pragma unroll
    for (int i = 0; i < 4; ++i) {
        Bs[0][bdst[i] + 0]   = br[i].x; Bs[0][bdst[i] + 132] = br[i].y;
        Bs[0][bdst[i] + 264] = br[i].z; Bs[0][bdst[i] + 396] = br[i].w;
    }

    for (int kt = 0; kt < nkt; ++kt) {
        __syncthreads();
        const int cur = kt & 1;
        const bool more = (kt + 1 < nkt);
        float4 nva0, nva1, nvb0, nvb1; uint2 nia0, nia1;
        if (more) {
            const int k0n = (kt + 1) * 32;
#pragma unroll
            for (int i = 0; i < 4; ++i) br[i] = *(const float4*)(bsrc[i] + k0n);
            const long kb0 = (long)(kt + 1) * 2 * MST, kb1 = kb0 + MST;
            nva0 = *(const float4*)(vbase + kb0); nva1 = *(const float4*)(vbase + kb0 + 4);
            nvb0 = *(const float4*)(vbase + kb1); nvb1 = *(const float4*)(vbase + kb1 + 4);
            nia0 = *(const uint2*)(ibase + kb0);  nia1 = *(const uint2*)(ibase + kb1);
        }
        const float vcur[2][8] = {
            {va0.x, va0.y, va0.z, va0.w, va1.x, va1.y, va1.z, va1.w},
            {vb0.x, vb0.y, vb0.z, vb0.w, vb1.x, vb1.y, vb1.z, vb1.w}};
        const int icur[2][8] = {
            {(int)(ia0.x & 255), (int)((ia0.x >> 8) & 255), (int)((ia0.x >> 16) & 255),
             (int)(ia0.x >> 24), (int)(ia0.y & 255), (int)((ia0.y >> 8) & 255),
             (int)((ia0.y >> 16) & 255), (int)(ia0.y >> 24)},
            {(int)(ia1.x & 255), (int)((ia1.x >> 8) & 255), (int)((ia1.x >> 16) & 255),
             (int)(ia1.x >> 24), (int)(ia1.y & 255), (int)((ia1.y >> 8) & 255),
             (int)((ia1.y >> 16) & 255), (int)(ia1.y >> 24)}};
#pragma unroll
        for (int r = 0; r < 8; ++r)
#pragma unroll
            for (int kb = 0; kb < 2; ++kb) {
                const float v = vcur[kb][r];
                const int kw = kb * 16 + icur[kb][r];
                const float* bp = &Bs[cur][kw * 132 + tx * 4];
                const float4 b0 = *(const float4*)bp;
                const float4 b1 = *(const float4*)(bp + 64);
                acc[r][0][0] += v * b0.x; acc[r][0][1] += v * b0.y;
                acc[r][0][2] += v * b0.z; acc[r][0][3] += v * b0.w;
                acc[r][1][0] += v * b1.x; acc[r][1][1] += v * b1.y;
                acc[r][1][2] += v * b1.z; acc[r][1][3] += v * b1.w;
            }
        if (more) {
            const int nxt = cur ^ 1;
#pragma unroll
            for (int i = 0; i < 4; ++i) {
                Bs[nxt][bdst[i] + 0]   = br[i].x; Bs[nxt][bdst[i] + 132] = br[i].y;
                Bs[nxt][bdst[i] + 264] = br[i].z; Bs[nxt][bdst[i] + 396] = br[i].w;
            }
            va0 = nva0; va1 = nva1; vb0 = nvb0; vb1 = nvb1; ia0 = nia0; ia1 = nia1;
        }
    }

    if (LWTA_OUT) {
#pragma unroll
        for (int r = 0; r < 8; ++r) {
            const long row = m0 + ty * 8 + r;
#pragma unroll
            for (int g = 0; g < 2; ++g) {
                float v1 = -3.f, v2 = -3.f; int i1v = 0, bHi = 0;
#pragma unroll
                for (int d = 0; d < 4; ++d) {
                    const long j = n0 + g * 64 + tx * 4 + d;
                    const float pre = acc[r][g][d] + bias[j];
                    const float cv = fminf(fmaxf(pre, -1.f), 1.f);
                    const int li = (tx & 3) * 4 + d;
                    if (cv > v1) { v2 = v1; v1 = cv; i1v = li; }
                    else if (cv > v2) v2 = cv;
                    bHi |= (pre > 1.f - eps && pre < 1.f + eps) ? 1 : 0;
                }
#pragma unroll
                for (int mk = 1; mk <= 2; mk <<= 1) {
                    const float ov1 = __shfl_xor(v1, mk);
                    const int   oi1 = __shfl_xor(i1v, mk);
                    const float ov2 = __shfl_xor(v2, mk);
                    bHi |= __shfl_xor(bHi, mk);
                    if (ov1 > v1 || (ov1 == v1 && oi1 < i1v)) {
                        v2 = fmaxf(v1, ov2); v1 = ov1; i1v = oi1;
                    } else v2 = fmaxf(v2, ov1);
                }
                if ((tx & 3) == 0) {
                    const bool stable = (v1 >= 1.f) && (v2 >= 1.f) && !bHi;
                    const int unc = ((v1 - v2 <= eps) && !stable) || (v1 <= -1.f + eps);
                    const long blk = (n0 >> 4) + g * 4 + (tx >> 2);
                    vOut[blk * MST + row] = v1;
                    iOut[blk * MST + row] = (uint8_t)i1v;
                    fOut[blk * MST + row] = (uint8_t)unc;
                }
            }
        }
    } else {
#pragma unroll
        for (int r = 0; r < 8; ++r) {
            const long row = m0 + ty * 8 + r;
#pragma unroll
            for (int g = 0; g < 2; ++g) {
                const long j = n0 + g * 64 + tx * 4;
                float4 o;
                o.x = acc[r][g][0] + bias[j + 0];
                o.y = acc[r][g][1] + bias[j + 1];
                o.z = acc[r][g][2] + bias[j + 2];
                o.w = acc[r][g][3] + bias[j + 3];
                *(float4*)&dOut[row * (long)N + j] = o;
            }
        }
    }
}

// ---------------------------------------------------------------------------
// k2b: fp64 resolve of flagged L2 blocks (transposed metadata).
__global__ __launch_bounds__(256)
void k2_resolve(const double* __restrict__ vA, const uint8_t* __restrict__ iA,
                const float* __restrict__ W2r, const float* __restrict__ bias,
                const uint8_t* __restrict__ fIn, uint8_t* __restrict__ iFix,
                float* __restrict__ vFix)
{
    const int gtid = blockIdx.x * 256 + threadIdx.x;
    const int wid = gtid >> 6, lane = gtid & 63;
    const long per = (256L * MST) / ((gridDim.x * 256) >> 6);
    const long s0 = (long)wid * per;
    for (long c = 0; c < per; c += 64) {
        unsigned long long mask = __ballot(fIn[s0 + c + lane] != 0);
        while (mask) {
            const int bit = __builtin_ctzll(mask); mask &= mask - 1;
            const long s = s0 + c + bit;
            const int gblk = (int)(s >> 13); const long row = s & (MST - 1);
            double hv[4]; int kp[4];
#pragma unroll
            for (int q = 0; q < 4; ++q) {
                const int b = lane * 4 + q;
                hv[q] = vA[(long)b * MST + row];
                kp[q] = b * 16 + (int)iA[(long)b * MST + row];
            }
            double best = -3.0; int bi = 0;
            for (int u = 0; u < 16; ++u) {
                const float* wr = &W2r[(long)(gblk * 16 + u) * 4096];
                double su = hv[0] * (double)wr[kp[0]] + hv[1] * (double)wr[kp[1]]
                          + hv[2] * (double)wr[kp[2]] + hv[3] * (double)wr[kp[3]];
#pragma unroll
                for (int off = 32; off; off >>= 1) su += __shfl_xor(su, off);
                const double xu = fmin(fmax(su + (double)bias[gblk * 16 + u], -1.0), 1.0);
                if (xu > best) { best = xu; bi = u; }
            }
            if (lane == 0) { iFix[s] = (uint8_t)bi; vFix[s] = (float)best; }
        }
    }
}

// ---------------------------------------------------------------------------
extern "C" void kernel_launch(void* const* d_in, const int* in_sizes, int n_in,
                              void* d_out, int out_size, void* d_ws, size_t ws_size,
                              hipStream_t stream)
{
    const float* x    = (const float*)d_in[0];
    const float* W1   = (const float*)d_in[1];
    const float* b1   = (const float*)d_in[2];
    const float* W2   = (const float*)d_in[3];
    const float* b2   = (const float*)d_in[4];
    const float* Wout = (const float*)d_in[5];
    const float* bout = (const float*)d_in[6];
    float* out = (float*)d_out;
    (void)in_sizes; (void)n_in; (void)out_size; (void)ws_size;

    const int B = 8192, Din = 1024, H = 4096, Dout = 1024;

    char* ws = (char*)d_ws;
    double*  v1d = (double*)ws;                       // 16 MB [256][8192]
    float*   v1f = (float*)(ws + (16ll << 20));       //  8 MB
    uint8_t* i1  = (uint8_t*)(ws + (24ll << 20));     //  2 MB
    uint8_t* f1  = (uint8_t*)(ws + (26ll << 20));     //  2 MB
    float*   v2f = (float*)(ws + (28ll << 20));       //  8 MB
    uint8_t* i2  = (uint8_t*)(ws + (36ll << 20));     //  2 MB
    uint8_t* f2  = (uint8_t*)(ws + (38ll << 20));     //  2 MB

    dim3 blk(256);
    k1a_dense_f32_flags<<<dim3(H / 256, B / 128), blk, 0, stream>>>(
        x, W1, b1, Din, i1, f1);
    k1b_winner_f64<<<dim3(H / 128, B / 128), blk, 0, stream>>>(
        x, W1, b1, Din, i1, v1d, v1f);
    k1_resolve<<<1024, blk, 0, stream>>>(x, W1, b1, f1, i1, v1d, v1f);
    sparse_gemm_v2<true><<<dim3(H / 128, B / 128), blk, 0, stream>>>(
        v1f, i1, W2, b2, H, EPS2, v2f, i2, f2, nullptr, H);
    k2_resolve<<<1024, blk, 0, stream>>>(v1d, i1, W2, b2, f2, i2, v2f);
    sparse_gemm_v2<false><<<dim3(Dout / 128, B / 128), blk, 0, stream>>>(
        v2f, i2, Wout, bout, H, 0.f, nullptr, nullptr, nullptr, out, Dout);
}

// Round 6
// 3452.420 us; speedup vs baseline: 7.0232x; 7.0232x over previous
//
#include <hip/hip_runtime.h>
#include <stdint.h>

// LWTA MLP, decision/value-split + latency-pipelined sparse GEMMs.
//   k1a: dense fp32 GEMM (LDS-staged, 2-barrier) -> winner idx + flags
//   k1b: fp64 winner-value recompute (1/16 FLOPs)
//   k1c: fp64 exact resolve of flagged L1 blocks
//   k2a: sparse fp32 GEMM, single-barrier double-buffered LDS, reg metadata
//   k2b: fp64 resolve of flagged L2 blocks
//   k3 : sparse fp32 GEMM -> dense out
// Metadata arrays are TRANSPOSED [kblock][8192] so sparse GEMMs fetch
// per-row metadata as broadcast float4/uint2 loads one tile ahead.
//
// NOTE: no __launch_bounds__ min-waves anywhere. Round-5 regression (24ms):
// (256,2)/(256,3) capped VGPRs below the live set (acc alone is 64-128)
// -> scratch spills -> 26 GB/dispatch of spill stores, VALUBusy 4%.

#define EPS1 3.0e-4f
#define EPS2 5.0e-5f
#define MST  8192L   // metadata row stride (batch size)

// ---------------------------------------------------------------------------
// k1a: dense fp32 GEMM, 128x256 tile, BK=32, LDS-staged (round-4 proven form).
#define BSTR1 260

__global__ __launch_bounds__(256)
void k1a_dense_f32_flags(const float* __restrict__ A, const float* __restrict__ Bw,
                         const float* __restrict__ bias, int K,
                         uint8_t* __restrict__ iOut, uint8_t* __restrict__ fOut)
{
    __shared__ float As[32 * 132];
    __shared__ float Bs[32 * BSTR1];
    const int t = threadIdx.x, tx = t & 15, ty = t >> 4;
    const long m0 = (long)blockIdx.y * 128, n0 = (long)blockIdx.x * 256;

    float acc[8][4][4];
#pragma unroll
    for (int r = 0; r < 8; ++r)
#pragma unroll
        for (int g = 0; g < 4; ++g)
#pragma unroll
            for (int d = 0; d < 4; ++d) acc[r][g][d] = 0.f;

    for (int k0 = 0; k0 < K; k0 += 32) {
        __syncthreads();
        // B tile: 256 cols x 8 quads = 2048 float4 slots -> 8 iters
#pragma unroll
        for (int i = 0; i < 8; ++i) {
            const int f = i * 256 + t, col = f >> 3, kq = (f & 7) * 4;
            const float4 w = *(const float4*)&Bw[(n0 + col) * (long)K + k0 + kq];
            Bs[(kq + 0) * BSTR1 + col] = w.x;
            Bs[(kq + 1) * BSTR1 + col] = w.y;
            Bs[(kq + 2) * BSTR1 + col] = w.z;
            Bs[(kq + 3) * BSTR1 + col] = w.w;
        }
        // A tile: 128 rows x 8 quads = 1024 slots -> 4 iters
#pragma unroll
        for (int i = 0; i < 4; ++i) {
            const int f = i * 256 + t, row = f >> 3, kq = (f & 7) * 4;
            const float4 a = *(const float4*)&A[(m0 + row) * (long)K + k0 + kq];
            As[(kq + 0) * 132 + row] = a.x;
            As[(kq + 1) * 132 + row] = a.y;
            As[(kq + 2) * 132 + row] = a.z;
            As[(kq + 3) * 132 + row] = a.w;
        }
        __syncthreads();
#pragma unroll
        for (int kk = 0; kk < 32; ++kk) {
            const float4 a0 = *(const float4*)&As[kk * 132 + ty * 8];
            const float4 a1 = *(const float4*)&As[kk * 132 + ty * 8 + 4];
            float4 bb[4];
#pragma unroll
            for (int g = 0; g < 4; ++g)
                bb[g] = *(const float4*)&Bs[kk * BSTR1 + g * 64 + tx * 4];
            const float arr[8] = {a0.x, a0.y, a0.z, a0.w, a1.x, a1.y, a1.z, a1.w};
#pragma unroll
            for (int r = 0; r < 8; ++r)
#pragma unroll
                for (int g = 0; g < 4; ++g) {
                    acc[r][g][0] += arr[r] * bb[g].x;
                    acc[r][g][1] += arr[r] * bb[g].y;
                    acc[r][g][2] += arr[r] * bb[g].z;
                    acc[r][g][3] += arr[r] * bb[g].w;
                }
        }
    }

#pragma unroll
    for (int r = 0; r < 8; ++r) {
        const long row = m0 + ty * 8 + r;
#pragma unroll
        for (int g = 0; g < 4; ++g) {
            float v1 = -3.f, v2 = -3.f; int i1v = 0, bHi = 0;
#pragma unroll
            for (int d = 0; d < 4; ++d) {
                const long j = n0 + g * 64 + tx * 4 + d;
                const float pre = acc[r][g][d] + bias[j];
                const float c = fminf(fmaxf(pre, -1.f), 1.f);
                const int li = (tx & 3) * 4 + d;
                if (c > v1) { v2 = v1; v1 = c; i1v = li; }
                else if (c > v2) v2 = c;
                bHi |= (pre > 1.f - EPS1 && pre < 1.f + EPS1) ? 1 : 0;
            }
#pragma unroll
            for (int mk = 1; mk <= 2; mk <<= 1) {
                const float ov1 = __shfl_xor(v1, mk);
                const int   oi1 = __shfl_xor(i1v, mk);
                const float ov2 = __shfl_xor(v2, mk);
                bHi |= __shfl_xor(bHi, mk);
                if (ov1 > v1 || (ov1 == v1 && oi1 < i1v)) {
                    v2 = fmaxf(v1, ov2); v1 = ov1; i1v = oi1;
                } else v2 = fmaxf(v2, ov1);
            }
            if ((tx & 3) == 0) {
                const bool stable = (v1 >= 1.f) && (v2 >= 1.f) && !bHi;
                const int unc = ((v1 - v2 <= EPS1) && !stable) || (v1 <= -1.f + EPS1);
                const long blk = (n0 >> 4) + g * 4 + (tx >> 2);
                iOut[blk * MST + row] = (uint8_t)i1v;
                fOut[blk * MST + row] = (uint8_t)unc;
            }
        }
    }
}

// ---------------------------------------------------------------------------
// k1b: fp64 winner-value recompute, transposed metadata.
__global__ __launch_bounds__(256)
void k1b_winner_f64(const float* __restrict__ A, const float* __restrict__ Bw,
                    const float* __restrict__ bias, int K,
                    const uint8_t* __restrict__ iIn,
                    double* __restrict__ vOutD, float* __restrict__ vOutF)
{
    __shared__ float4 As2[128 * 9];
    __shared__ float4 Bs2[128 * 9];
    const int t = threadIdx.x, w = t & 7, r0 = t >> 3;
    const long m0 = (long)blockIdx.y * 128, n0 = (long)blockIdx.x * 128;

    long tix[4]; int wj[4]; double acc[4] = {0.0, 0.0, 0.0, 0.0};
#pragma unroll
    for (int q = 0; q < 4; ++q) {
        const int row = r0 + 32 * q;
        tix[q] = (long)(blockIdx.x * 8 + w) * MST + (m0 + row);
        wj[q] = w * 16 + (int)iIn[tix[q]];
    }
    for (int k0 = 0; k0 < K; k0 += 32) {
        __syncthreads();
#pragma unroll
        for (int i = 0; i < 4; ++i) {
            const int f = i * 256 + t, rc = f >> 3, kq = f & 7;
            As2[rc * 9 + (kq ^ (rc & 7))] = *(const float4*)&A[(m0 + rc) * (long)K + k0 + kq * 4];
            Bs2[rc * 9 + (kq ^ (rc & 7))] = *(const float4*)&Bw[(n0 + rc) * (long)K + k0 + kq * 4];
        }
        __syncthreads();
#pragma unroll
        for (int q = 0; q < 4; ++q) {
            const int ra = (r0 + 32 * q) * 9, sa = (r0 + 32 * q) & 7;
            const int rb = wj[q] * 9, sb = wj[q] & 7;
            double s = acc[q];
#pragma unroll
            for (int kq = 0; kq < 8; ++kq) {
                const float4 xa = As2[ra + (kq ^ sa)];
                const float4 wb = Bs2[rb + (kq ^ sb)];
                s += (double)xa.x * wb.x + (double)xa.y * wb.y
                   + (double)xa.z * wb.z + (double)xa.w * wb.w;
            }
            acc[q] = s;
        }
    }
#pragma unroll
    for (int q = 0; q < 4; ++q) {
        double v = acc[q] + (double)bias[n0 + wj[q]];
        v = fmin(fmax(v, -1.0), 1.0);
        vOutD[tix[q]] = v;
        vOutF[tix[q]] = (float)v;
    }
}

// ---------------------------------------------------------------------------
// k1c: fp64 resolve of flagged L1 blocks (transposed index space).
__global__ __launch_bounds__(256)
void k1_resolve(const float* __restrict__ A, const float* __restrict__ Bw,
                const float* __restrict__ bias, const uint8_t* __restrict__ fIn,
                uint8_t* __restrict__ iFix, double* __restrict__ vOutD,
                float* __restrict__ vOutF)
{
    const int gtid = blockIdx.x * 256 + threadIdx.x;
    const int wid = gtid >> 6, lane = gtid & 63;
    const long per = (256L * MST) / ((gridDim.x * 256) >> 6);
    const long s0 = (long)wid * per;
    for (long c = 0; c < per; c += 64) {
        unsigned long long mask = __ballot(fIn[s0 + c + lane] != 0);
        while (mask) {
            const int bit = __builtin_ctzll(mask); mask &= mask - 1;
            const long s = s0 + c + bit;
            const int blk = (int)(s >> 13); const long row = s & (MST - 1);
            const float4* xp = (const float4*)&A[row * 1024 + lane * 16];
            const float4 x0 = xp[0], x1 = xp[1], x2 = xp[2], x3 = xp[3];
            double best = -3.0; int bi = 0;
            for (int u = 0; u < 16; ++u) {
                const float4* wp = (const float4*)&Bw[(long)(blk * 16 + u) * 1024 + lane * 16];
                const float4 w0 = wp[0], w1 = wp[1], w2 = wp[2], w3 = wp[3];
                double su = (double)x0.x * w0.x + (double)x0.y * w0.y
                          + (double)x0.z * w0.z + (double)x0.w * w0.w
                          + (double)x1.x * w1.x + (double)x1.y * w1.y
                          + (double)x1.z * w1.z + (double)x1.w * w1.w
                          + (double)x2.x * w2.x + (double)x2.y * w2.y
                          + (double)x2.z * w2.z + (double)x2.w * w2.w
                          + (double)x3.x * w3.x + (double)x3.y * w3.y
                          + (double)x3.z * w3.z + (double)x3.w * w3.w;
#pragma unroll
                for (int off = 32; off; off >>= 1) su += __shfl_xor(su, off);
                const double xu = fmin(fmax(su + (double)bias[blk * 16 + u], -1.0), 1.0);
                if (xu > best) { best = xu; bi = u; }
            }
            if (lane == 0) { iFix[s] = (uint8_t)bi; vOutD[s] = best; vOutF[s] = (float)best; }
        }
    }
}

// ---------------------------------------------------------------------------
// Sparse GEMM v2: single-barrier double-buffered LDS, reg-prefetched B tile
// and metadata (transposed [kblock][M] layout). 128x128 tile, BK=32.
template<bool LWTA_OUT>
__global__ __launch_bounds__(256)
void sparse_gemm_v2(const float* __restrict__ vA, const uint8_t* __restrict__ iA,
                    const float* __restrict__ Bw, const float* __restrict__ bias,
                    int K, float eps,
                    float* __restrict__ vOut, uint8_t* __restrict__ iOut,
                    uint8_t* __restrict__ fOut, float* __restrict__ dOut, int N)
{
    __shared__ float Bs[2][32 * 132];
    const int t = threadIdx.x, tx = t & 15, ty = t >> 4;
    const long m0 = (long)blockIdx.y * 128, n0 = (long)blockIdx.x * 128;
    const int nkt = K / 32;

    float acc[8][2][4];
#pragma unroll
    for (int r = 0; r < 8; ++r)
#pragma unroll
        for (int g = 0; g < 2; ++g)
#pragma unroll
            for (int d = 0; d < 4; ++d) acc[r][g][d] = 0.f;

    const float* bsrc[4]; int bdst[4];
#pragma unroll
    for (int i = 0; i < 4; ++i) {
        const int f = i * 256 + t, col = f >> 3, kq = (f & 7) * 4;
        bsrc[i] = &Bw[(n0 + col) * (long)K + kq];
        bdst[i] = kq * 132 + col;
    }
    const float*   vbase = vA + m0 + ty * 8;
    const uint8_t* ibase = iA + m0 + ty * 8;

    // prologue: tile 0
    float4 br[4];
#pragma unroll
    for (int i = 0; i < 4; ++i) br[i] = *(const float4*)(bsrc[i]);
    float4 va0 = *(const float4*)(vbase);
    float4 va1 = *(const float4*)(vbase + 4);
    float4 vb0 = *(const float4*)(vbase + MST);
    float4 vb1 = *(const float4*)(vbase + MST + 4);
    uint2  ia0 = *(const uint2*)(ibase);
    uint2  ia1 = *(const uint2*)(ibase + MST);
#pragma unroll
    for (int i = 0; i < 4; ++i) {
        Bs[0][bdst[i] + 0]   = br[i].x; Bs[0][bdst[i] + 132] = br[i].y;
        Bs[0][bdst[i] + 264] = br[i].z; Bs[0][bdst[i] + 396] = br[i].w;
    }

    for (int kt = 0; kt < nkt; ++kt) {
        __syncthreads();
        const int cur = kt & 1;
        const bool more = (kt + 1 < nkt);
        float4 nva0, nva1, nvb0, nvb1; uint2 nia0, nia1;
        if (more) {
            const int k0n = (kt + 1) * 32;
#pragma unroll
            for (int i = 0; i < 4; ++i) br[i] = *(const float4*)(bsrc[i] + k0n);
            const long kb0 = (long)(kt + 1) * 2 * MST, kb1 = kb0 + MST;
            nva0 = *(const float4*)(vbase + kb0); nva1 = *(const float4*)(vbase + kb0 + 4);
            nvb0 = *(const float4*)(vbase + kb1); nvb1 = *(const float4*)(vbase + kb1 + 4);
            nia0 = *(const uint2*)(ibase + kb0);  nia1 = *(const uint2*)(ibase + kb1);
        }
        const float vcur[2][8] = {
            {va0.x, va0.y, va0.z, va0.w, va1.x, va1.y, va1.z, va1.w},
            {vb0.x, vb0.y, vb0.z, vb0.w, vb1.x, vb1.y, vb1.z, vb1.w}};
        const int icur[2][8] = {
            {(int)(ia0.x & 255), (int)((ia0.x >> 8) & 255), (int)((ia0.x >> 16) & 255),
             (int)(ia0.x >> 24), (int)(ia0.y & 255), (int)((ia0.y >> 8) & 255),
             (int)((ia0.y >> 16) & 255), (int)(ia0.y >> 24)},
            {(int)(ia1.x & 255), (int)((ia1.x >> 8) & 255), (int)((ia1.x >> 16) & 255),
             (int)(ia1.x >> 24), (int)(ia1.y & 255), (int)((ia1.y >> 8) & 255),
             (int)((ia1.y >> 16) & 255), (int)(ia1.y >> 24)}};
#pragma unroll
        for (int r = 0; r < 8; ++r)
#pragma unroll
            for (int kb = 0; kb < 2; ++kb) {
                const float v = vcur[kb][r];
                const int kw = kb * 16 + icur[kb][r];
                const float* bp = &Bs[cur][kw * 132 + tx * 4];
                const float4 b0 = *(const float4*)bp;
                const float4 b1 = *(const float4*)(bp + 64);
                acc[r][0][0] += v * b0.x; acc[r][0][1] += v * b0.y;
                acc[r][0][2] += v * b0.z; acc[r][0][3] += v * b0.w;
                acc[r][1][0] += v * b1.x; acc[r][1][1] += v * b1.y;
                acc[r][1][2] += v * b1.z; acc[r][1][3] += v * b1.w;
            }
        if (more) {
            const int nxt = cur ^ 1;
#pragma unroll
            for (int i = 0; i < 4; ++i) {
                Bs[nxt][bdst[i] + 0]   = br[i].x; Bs[nxt][bdst[i] + 132] = br[i].y;
                Bs[nxt][bdst[i] + 264] = br[i].z; Bs[nxt][bdst[i] + 396] = br[i].w;
            }
            va0 = nva0; va1 = nva1; vb0 = nvb0; vb1 = nvb1; ia0 = nia0; ia1 = nia1;
        }
    }

    if (LWTA_OUT) {
#pragma unroll
        for (int r = 0; r < 8; ++r) {
            const long row = m0 + ty * 8 + r;
#pragma unroll
            for (int g = 0; g < 2; ++g) {
                float v1 = -3.f, v2 = -3.f; int i1v = 0, bHi = 0;
#pragma unroll
                for (int d = 0; d < 4; ++d) {
                    const long j = n0 + g * 64 + tx * 4 + d;
                    const float pre = acc[r][g][d] + bias[j];
                    const float cv = fminf(fmaxf(pre, -1.f), 1.f);
                    const int li = (tx & 3) * 4 + d;
                    if (cv > v1) { v2 = v1; v1 = cv; i1v = li; }
                    else if (cv > v2) v2 = cv;
                    bHi |= (pre > 1.f - eps && pre < 1.f + eps) ? 1 : 0;
                }
#pragma unroll
                for (int mk = 1; mk <= 2; mk <<= 1) {
                    const float ov1 = __shfl_xor(v1, mk);
                    const int   oi1 = __shfl_xor(i1v, mk);
                    const float ov2 = __shfl_xor(v2, mk);
                    bHi |= __shfl_xor(bHi, mk);
                    if (ov1 > v1 || (ov1 == v1 && oi1 < i1v)) {
                        v2 = fmaxf(v1, ov2); v1 = ov1; i1v = oi1;
                    } else v2 = fmaxf(v2, ov1);
                }
                if ((tx & 3) == 0) {
                    const bool stable = (v1 >= 1.f) && (v2 >= 1.f) && !bHi;
                    const int unc = ((v1 - v2 <= eps) && !stable) || (v1 <= -1.f + eps);
                    const long blk = (n0 >> 4) + g * 4 + (tx >> 2);
                    vOut[blk * MST + row] = v1;
                    iOut[blk * MST + row] = (uint8_t)i1v;
                    fOut[blk * MST + row] = (uint8_t)unc;
                }
            }
        }
    } else {
#pragma unroll
        for (int r = 0; r < 8; ++r) {
            const long row = m0 + ty * 8 + r;
#pragma unroll
            for (int g = 0; g < 2; ++g) {
                const long j = n0 + g * 64 + tx * 4;
                float4 o;
                o.x = acc[r][g][0] + bias[j + 0];
                o.y = acc[r][g][1] + bias[j + 1];
                o.z = acc[r][g][2] + bias[j + 2];
                o.w = acc[r][g][3] + bias[j + 3];
                *(float4*)&dOut[row * (long)N + j] = o;
            }
        }
    }
}

// ---------------------------------------------------------------------------
// k2b: fp64 resolve of flagged L2 blocks (transposed metadata).
__global__ __launch_bounds__(256)
void k2_resolve(const double* __restrict__ vA, const uint8_t* __restrict__ iA,
                const float* __restrict__ W2r, const float* __restrict__ bias,
                const uint8_t* __restrict__ fIn, uint8_t* __restrict__ iFix,
                float* __restrict__ vFix)
{
    const int gtid = blockIdx.x * 256 + threadIdx.x;
    const int wid = gtid >> 6, lane = gtid & 63;
    const long per = (256L * MST) / ((gridDim.x * 256) >> 6);
    const long s0 = (long)wid * per;
    for (long c = 0; c < per; c += 64) {
        unsigned long long mask = __ballot(fIn[s0 + c + lane] != 0);
        while (mask) {
            const int bit = __builtin_ctzll(mask); mask &= mask - 1;
            const long s = s0 + c + bit;
            const int gblk = (int)(s >> 13); const long row = s & (MST - 1);
            double hv[4]; int kp[4];
#pragma unroll
            for (int q = 0; q < 4; ++q) {
                const int b = lane * 4 + q;
                hv[q] = vA[(long)b * MST + row];
                kp[q] = b * 16 + (int)iA[(long)b * MST + row];
            }
            double best = -3.0; int bi = 0;
            for (int u = 0; u < 16; ++u) {
                const float* wr = &W2r[(long)(gblk * 16 + u) * 4096];
                double su = hv[0] * (double)wr[kp[0]] + hv[1] * (double)wr[kp[1]]
                          + hv[2] * (double)wr[kp[2]] + hv[3] * (double)wr[kp[3]];
#pragma unroll
                for (int off = 32; off; off >>= 1) su += __shfl_xor(su, off);
                const double xu = fmin(fmax(su + (double)bias[gblk * 16 + u], -1.0), 1.0);
                if (xu > best) { best = xu; bi = u; }
            }
            if (lane == 0) { iFix[s] = (uint8_t)bi; vFix[s] = (float)best; }
        }
    }
}

// ---------------------------------------------------------------------------
extern "C" void kernel_launch(void* const* d_in, const int* in_sizes, int n_in,
                              void* d_out, int out_size, void* d_ws, size_t ws_size,
                              hipStream_t stream)
{
    const float* x    = (const float*)d_in[0];
    const float* W1   = (const float*)d_in[1];
    const float* b1   = (const float*)d_in[2];
    const float* W2   = (const float*)d_in[3];
    const float* b2   = (const float*)d_in[4];
    const float* Wout = (const float*)d_in[5];
    const float* bout = (const float*)d_in[6];
    float* out = (float*)d_out;
    (void)in_sizes; (void)n_in; (void)out_size; (void)ws_size;

    const int B = 8192, Din = 1024, H = 4096, Dout = 1024;

    char* ws = (char*)d_ws;
    double*  v1d = (double*)ws;                       // 16 MB [256][8192]
    float*   v1f = (float*)(ws + (16ll << 20));       //  8 MB
    uint8_t* i1  = (uint8_t*)(ws + (24ll << 20));     //  2 MB
    uint8_t* f1  = (uint8_t*)(ws + (26ll << 20));     //  2 MB
    float*   v2f = (float*)(ws + (28ll << 20));       //  8 MB
    uint8_t* i2  = (uint8_t*)(ws + (36ll << 20));     //  2 MB
    uint8_t* f2  = (uint8_t*)(ws + (38ll << 20));     //  2 MB

    dim3 blk(256);
    k1a_dense_f32_flags<<<dim3(H / 256, B / 128), blk, 0, stream>>>(
        x, W1, b1, Din, i1, f1);
    k1b_winner_f64<<<dim3(H / 128, B / 128), blk, 0, stream>>>(
        x, W1, b1, Din, i1, v1d, v1f);
    k1_resolve<<<1024, blk, 0, stream>>>(x, W1, b1, f1, i1, v1d, v1f);
    sparse_gemm_v2<true><<<dim3(H / 128, B / 128), blk, 0, stream>>>(
        v1f, i1, W2, b2, H, EPS2, v2f, i2, f2, nullptr, H);
    k2_resolve<<<1024, blk, 0, stream>>>(v1d, i1, W2, b2, f2, i2, v2f);
    sparse_gemm_v2<false><<<dim3(Dout / 128, B / 128), blk, 0, stream>>>(
        v2f, i2, Wout, bout, H, 0.f, nullptr, nullptr, nullptr, out, Dout);
}

// Round 7
// 2829.854 us; speedup vs baseline: 8.5684x; 1.2200x over previous
//
#include <hip/hip_runtime.h>
#include <stdint.h>

// LWTA MLP, decision/value-split.
//   k1a: dense fp32 GEMM (LDS-staged) -> winner idx + uncertainty flags
//   k1b: fp64 winner-value recompute (1/16 FLOPs)
//   k1c: fp64 exact resolve of flagged L1 blocks
//   k2a: sparse fp32 GEMM v3 (wave-per-row gather, conflict-free LDS)
//   k2b: fp64 resolve of flagged L2 blocks
//   k3 : sparse fp32 GEMM v3 -> dense out
// Sparse v3: BK=16 (one LWTA block), N_blk=256, wave owns 16 rows; the
// winner row read is ds_read_b128 of a CONTIGUOUS 1KB LDS row (kw uniform
// per wave via readlane) -> zero bank conflicts; v2 had 2.26e8 conflict
// cycles from 4 quarter-waves hitting different rows at stride 132.
// Metadata TRANSPOSED [kblock][8192]. No __launch_bounds__ min-waves
// (round-5 lesson: caps below live set -> 26GB of spill traffic).

#define EPS1 3.0e-4f
#define EPS2 5.0e-5f
#define MST  8192L   // metadata row stride (batch size)

// ---------------------------------------------------------------------------
// k1a: dense fp32 GEMM, 128x256 tile, BK=32, LDS-staged (proven form).
#define BSTR1 260

__global__ __launch_bounds__(256)
void k1a_dense_f32_flags(const float* __restrict__ A, const float* __restrict__ Bw,
                         const float* __restrict__ bias, int K,
                         uint8_t* __restrict__ iOut, uint8_t* __restrict__ fOut)
{
    __shared__ float As[32 * 132];
    __shared__ float Bs[32 * BSTR1];
    const int t = threadIdx.x, tx = t & 15, ty = t >> 4;
    const long m0 = (long)blockIdx.y * 128, n0 = (long)blockIdx.x * 256;

    float acc[8][4][4];
#pragma unroll
    for (int r = 0; r < 8; ++r)
#pragma unroll
        for (int g = 0; g < 4; ++g)
#pragma unroll
            for (int d = 0; d < 4; ++d) acc[r][g][d] = 0.f;

    for (int k0 = 0; k0 < K; k0 += 32) {
        __syncthreads();
#pragma unroll
        for (int i = 0; i < 8; ++i) {
            const int f = i * 256 + t, col = f >> 3, kq = (f & 7) * 4;
            const float4 w = *(const float4*)&Bw[(n0 + col) * (long)K + k0 + kq];
            Bs[(kq + 0) * BSTR1 + col] = w.x;
            Bs[(kq + 1) * BSTR1 + col] = w.y;
            Bs[(kq + 2) * BSTR1 + col] = w.z;
            Bs[(kq + 3) * BSTR1 + col] = w.w;
        }
#pragma unroll
        for (int i = 0; i < 4; ++i) {
            const int f = i * 256 + t, row = f >> 3, kq = (f & 7) * 4;
            const float4 a = *(const float4*)&A[(m0 + row) * (long)K + k0 + kq];
            As[(kq + 0) * 132 + row] = a.x;
            As[(kq + 1) * 132 + row] = a.y;
            As[(kq + 2) * 132 + row] = a.z;
            As[(kq + 3) * 132 + row] = a.w;
        }
        __syncthreads();
#pragma unroll
        for (int kk = 0; kk < 32; ++kk) {
            const float4 a0 = *(const float4*)&As[kk * 132 + ty * 8];
            const float4 a1 = *(const float4*)&As[kk * 132 + ty * 8 + 4];
            float4 bb[4];
#pragma unroll
            for (int g = 0; g < 4; ++g)
                bb[g] = *(const float4*)&Bs[kk * BSTR1 + g * 64 + tx * 4];
            const float arr[8] = {a0.x, a0.y, a0.z, a0.w, a1.x, a1.y, a1.z, a1.w};
#pragma unroll
            for (int r = 0; r < 8; ++r)
#pragma unroll
                for (int g = 0; g < 4; ++g) {
                    acc[r][g][0] += arr[r] * bb[g].x;
                    acc[r][g][1] += arr[r] * bb[g].y;
                    acc[r][g][2] += arr[r] * bb[g].z;
                    acc[r][g][3] += arr[r] * bb[g].w;
                }
        }
    }

#pragma unroll
    for (int r = 0; r < 8; ++r) {
        const long row = m0 + ty * 8 + r;
#pragma unroll
        for (int g = 0; g < 4; ++g) {
            float v1 = -3.f, v2 = -3.f; int i1v = 0, bHi = 0;
#pragma unroll
            for (int d = 0; d < 4; ++d) {
                const long j = n0 + g * 64 + tx * 4 + d;
                const float pre = acc[r][g][d] + bias[j];
                const float c = fminf(fmaxf(pre, -1.f), 1.f);
                const int li = (tx & 3) * 4 + d;
                if (c > v1) { v2 = v1; v1 = c; i1v = li; }
                else if (c > v2) v2 = c;
                bHi |= (pre > 1.f - EPS1 && pre < 1.f + EPS1) ? 1 : 0;
            }
#pragma unroll
            for (int mk = 1; mk <= 2; mk <<= 1) {
                const float ov1 = __shfl_xor(v1, mk);
                const int   oi1 = __shfl_xor(i1v, mk);
                const float ov2 = __shfl_xor(v2, mk);
                bHi |= __shfl_xor(bHi, mk);
                if (ov1 > v1 || (ov1 == v1 && oi1 < i1v)) {
                    v2 = fmaxf(v1, ov2); v1 = ov1; i1v = oi1;
                } else v2 = fmaxf(v2, ov1);
            }
            if ((tx & 3) == 0) {
                const bool stable = (v1 >= 1.f) && (v2 >= 1.f) && !bHi;
                const int unc = ((v1 - v2 <= EPS1) && !stable) || (v1 <= -1.f + EPS1);
                const long blk = (n0 >> 4) + g * 4 + (tx >> 2);
                iOut[blk * MST + row] = (uint8_t)i1v;
                fOut[blk * MST + row] = (uint8_t)unc;
            }
        }
    }
}

// ---------------------------------------------------------------------------
// k1b: fp64 winner-value recompute, transposed metadata.
__global__ __launch_bounds__(256)
void k1b_winner_f64(const float* __restrict__ A, const float* __restrict__ Bw,
                    const float* __restrict__ bias, int K,
                    const uint8_t* __restrict__ iIn,
                    double* __restrict__ vOutD, float* __restrict__ vOutF)
{
    __shared__ float4 As2[128 * 9];
    __shared__ float4 Bs2[128 * 9];
    const int t = threadIdx.x, w = t & 7, r0 = t >> 3;
    const long m0 = (long)blockIdx.y * 128, n0 = (long)blockIdx.x * 128;

    long tix[4]; int wj[4]; double acc[4] = {0.0, 0.0, 0.0, 0.0};
#pragma unroll
    for (int q = 0; q < 4; ++q) {
        const int row = r0 + 32 * q;
        tix[q] = (long)(blockIdx.x * 8 + w) * MST + (m0 + row);
        wj[q] = w * 16 + (int)iIn[tix[q]];
    }
    for (int k0 = 0; k0 < K; k0 += 32) {
        __syncthreads();
#pragma unroll
        for (int i = 0; i < 4; ++i) {
            const int f = i * 256 + t, rc = f >> 3, kq = f & 7;
            As2[rc * 9 + (kq ^ (rc & 7))] = *(const float4*)&A[(m0 + rc) * (long)K + k0 + kq * 4];
            Bs2[rc * 9 + (kq ^ (rc & 7))] = *(const float4*)&Bw[(n0 + rc) * (long)K + k0 + kq * 4];
        }
        __syncthreads();
#pragma unroll
        for (int q = 0; q < 4; ++q) {
            const int ra = (r0 + 32 * q) * 9, sa = (r0 + 32 * q) & 7;
            const int rb = wj[q] * 9, sb = wj[q] & 7;
            double s = acc[q];
#pragma unroll
            for (int kq = 0; kq < 8; ++kq) {
                const float4 xa = As2[ra + (kq ^ sa)];
                const float4 wb = Bs2[rb + (kq ^ sb)];
                s += (double)xa.x * wb.x + (double)xa.y * wb.y
                   + (double)xa.z * wb.z + (double)xa.w * wb.w;
            }
            acc[q] = s;
        }
    }
#pragma unroll
    for (int q = 0; q < 4; ++q) {
        double v = acc[q] + (double)bias[n0 + wj[q]];
        v = fmin(fmax(v, -1.0), 1.0);
        vOutD[tix[q]] = v;
        vOutF[tix[q]] = (float)v;
    }
}

// ---------------------------------------------------------------------------
// k1c: fp64 resolve of flagged L1 blocks.
__global__ __launch_bounds__(256)
void k1_resolve(const float* __restrict__ A, const float* __restrict__ Bw,
                const float* __restrict__ bias, const uint8_t* __restrict__ fIn,
                uint8_t* __restrict__ iFix, double* __restrict__ vOutD,
                float* __restrict__ vOutF)
{
    const int gtid = blockIdx.x * 256 + threadIdx.x;
    const int wid = gtid >> 6, lane = gtid & 63;
    const long per = (256L * MST) / ((gridDim.x * 256) >> 6);
    const long s0 = (long)wid * per;
    for (long c = 0; c < per; c += 64) {
        unsigned long long mask = __ballot(fIn[s0 + c + lane] != 0);
        while (mask) {
            const int bit = __builtin_ctzll(mask); mask &= mask - 1;
            const long s = s0 + c + bit;
            const int blk = (int)(s >> 13); const long row = s & (MST - 1);
            const float4* xp = (const float4*)&A[row * 1024 + lane * 16];
            const float4 x0 = xp[0], x1 = xp[1], x2 = xp[2], x3 = xp[3];
            double best = -3.0; int bi = 0;
            for (int u = 0; u < 16; ++u) {
                const float4* wp = (const float4*)&Bw[(long)(blk * 16 + u) * 1024 + lane * 16];
                const float4 w0 = wp[0], w1 = wp[1], w2 = wp[2], w3 = wp[3];
                double su = (double)x0.x * w0.x + (double)x0.y * w0.y
                          + (double)x0.z * w0.z + (double)x0.w * w0.w
                          + (double)x1.x * w1.x + (double)x1.y * w1.y
                          + (double)x1.z * w1.z + (double)x1.w * w1.w
                          + (double)x2.x * w2.x + (double)x2.y * w2.y
                          + (double)x2.z * w2.z + (double)x2.w * w2.w
                          + (double)x3.x * w3.x + (double)x3.y * w3.y
                          + (double)x3.z * w3.z + (double)x3.w * w3.w;
#pragma unroll
                for (int off = 32; off; off >>= 1) su += __shfl_xor(su, off);
                const double xu = fmin(fmax(su + (double)bias[blk * 16 + u], -1.0), 1.0);
                if (xu > best) { best = xu; bi = u; }
            }
            if (lane == 0) { iFix[s] = (uint8_t)bi; vOutD[s] = best; vOutF[s] = (float)best; }
        }
    }
}

// ---------------------------------------------------------------------------
// Sparse GEMM v3: BK=16 (one LWTA block), N_blk=256, M_blk=64 (4 waves x 16
// rows). Whole wave processes one A-row: winner (v,kw) wave-uniform via
// readlane, B-row gather = contiguous 1KB ds_read_b128 (conflict-free).
// Double-buffered LDS, single barrier per k-tile, reg-prefetched staging.
#define SB 260   // LDS row stride (words): 16 cols x 2 offsets = 32 banks on writes

template<bool LWTA_OUT>
__global__ __launch_bounds__(256)
void sparse_gemm_v3(const float* __restrict__ vA, const uint8_t* __restrict__ iA,
                    const float* __restrict__ Bw, const float* __restrict__ bias,
                    int K, float eps,
                    float* __restrict__ vOut, uint8_t* __restrict__ iOut,
                    uint8_t* __restrict__ fOut, float* __restrict__ dOut, int N)
{
    __shared__ float Bs[2][16 * SB];
    const int t = threadIdx.x;
    const int lane = t & 63;
    const int w = t >> 6;
    const long m0 = (long)blockIdx.y * 64;
    const long n0 = (long)blockIdx.x * 256;
    const long rbase = m0 + w * 16;
    const int nkt = K / 16;

    float acc[16][4];
#pragma unroll
    for (int r = 0; r < 16; ++r)
#pragma unroll
        for (int d = 0; d < 4; ++d) acc[r][d] = 0.f;

    // staging map: f = i*256+t -> col=f>>2 (0..255), kq=(f&3)*4
    const float* bsrc[4]; int bdst[4];
#pragma unroll
    for (int i = 0; i < 4; ++i) {
        const int f = i * 256 + t, col = f >> 2, kq = (f & 3) * 4;
        bsrc[i] = &Bw[(n0 + col) * (long)K + kq];
        bdst[i] = kq * SB + col;
    }
    const long mrow = rbase + (lane & 15);   // all lanes mirror the 16 rows

    // prologue: tile 0
    float4 br[4];
#pragma unroll
    for (int i = 0; i < 4; ++i) br[i] = *(const float4*)(bsrc[i]);
    float    va = vA[mrow];
    unsigned ia = iA[mrow];
#pragma unroll
    for (int i = 0; i < 4; ++i) {
        Bs[0][bdst[i] + 0*SB] = br[i].x; Bs[0][bdst[i] + 1*SB] = br[i].y;
        Bs[0][bdst[i] + 2*SB] = br[i].z; Bs[0][bdst[i] + 3*SB] = br[i].w;
    }

    for (int kt = 0; kt < nkt; ++kt) {
        __syncthreads();
        const int cur = kt & 1;
        const bool more = kt + 1 < nkt;
        float nva = 0.f; unsigned nia = 0;
        if (more) {
            const int k0n = (kt + 1) * 16;
#pragma unroll
            for (int i = 0; i < 4; ++i) br[i] = *(const float4*)(bsrc[i] + k0n);
            nva = vA[(long)(kt + 1) * MST + mrow];
            nia = iA[(long)(kt + 1) * MST + mrow];
        }
        const float* bb = &Bs[cur][0];
#pragma unroll
        for (int r = 0; r < 16; ++r) {
            const float v = __uint_as_float(
                __builtin_amdgcn_readlane(__float_as_uint(va), r));
            const int kw = __builtin_amdgcn_readlane((int)ia, r);
            const float4 b = *(const float4*)&bb[kw * SB + lane * 4];
            acc[r][0] += v * b.x; acc[r][1] += v * b.y;
            acc[r][2] += v * b.z; acc[r][3] += v * b.w;
        }
        if (more) {
            const int nxt = cur ^ 1;
#pragma unroll
            for (int i = 0; i < 4; ++i) {
                Bs[nxt][bdst[i] + 0*SB] = br[i].x; Bs[nxt][bdst[i] + 1*SB] = br[i].y;
                Bs[nxt][bdst[i] + 2*SB] = br[i].z; Bs[nxt][bdst[i] + 3*SB] = br[i].w;
            }
            va = nva; ia = nia;
        }
    }

    const float4 bv4 = *(const float4*)&bias[n0 + lane * 4];
    const float bias4[4] = {bv4.x, bv4.y, bv4.z, bv4.w};

    if (LWTA_OUT) {
#pragma unroll
        for (int r = 0; r < 16; ++r) {
            const long row = rbase + r;
            float v1 = -3.f, v2 = -3.f; int i1v = 0, bHi = 0;
#pragma unroll
            for (int d = 0; d < 4; ++d) {
                const float pre = acc[r][d] + bias4[d];
                const float cv = fminf(fmaxf(pre, -1.f), 1.f);
                const int li = (lane & 3) * 4 + d;
                if (cv > v1) { v2 = v1; v1 = cv; i1v = li; }
                else if (cv > v2) v2 = cv;
                bHi |= (pre > 1.f - eps && pre < 1.f + eps) ? 1 : 0;
            }
#pragma unroll
            for (int mk = 1; mk <= 2; mk <<= 1) {
                const float ov1 = __shfl_xor(v1, mk);
                const int   oi1 = __shfl_xor(i1v, mk);
                const float ov2 = __shfl_xor(v2, mk);
                bHi |= __shfl_xor(bHi, mk);
                if (ov1 > v1 || (ov1 == v1 && oi1 < i1v)) {
                    v2 = fmaxf(v1, ov2); v1 = ov1; i1v = oi1;
                } else v2 = fmaxf(v2, ov1);
            }
            if ((lane & 3) == 0) {
                const bool stable = (v1 >= 1.f) && (v2 >= 1.f) && !bHi;
                const int unc = ((v1 - v2 <= eps) && !stable) || (v1 <= -1.f + eps);
                const long blk = (n0 >> 4) + (lane >> 2);
                vOut[blk * MST + row] = v1;
                iOut[blk * MST + row] = (uint8_t)i1v;
                fOut[blk * MST + row] = (uint8_t)unc;
            }
        }
    } else {
#pragma unroll
        for (int r = 0; r < 16; ++r) {
            const long row = rbase + r;
            float4 o;
            o.x = acc[r][0] + bias4[0];
            o.y = acc[r][1] + bias4[1];
            o.z = acc[r][2] + bias4[2];
            o.w = acc[r][3] + bias4[3];
            *(float4*)&dOut[row * (long)N + n0 + lane * 4] = o;
        }
    }
}

// ---------------------------------------------------------------------------
// k2b: fp64 resolve of flagged L2 blocks (transposed metadata).
__global__ __launch_bounds__(256)
void k2_resolve(const double* __restrict__ vA, const uint8_t* __restrict__ iA,
                const float* __restrict__ W2r, const float* __restrict__ bias,
                const uint8_t* __restrict__ fIn, uint8_t* __restrict__ iFix,
                float* __restrict__ vFix)
{
    const int gtid = blockIdx.x * 256 + threadIdx.x;
    const int wid = gtid >> 6, lane = gtid & 63;
    const long per = (256L * MST) / ((gridDim.x * 256) >> 6);
    const long s0 = (long)wid * per;
    for (long c = 0; c < per; c += 64) {
        unsigned long long mask = __ballot(fIn[s0 + c + lane] != 0);
        while (mask) {
            const int bit = __builtin_ctzll(mask); mask &= mask - 1;
            const long s = s0 + c + bit;
            const int gblk = (int)(s >> 13); const long row = s & (MST - 1);
            double hv[4]; int kp[4];
#pragma unroll
            for (int q = 0; q < 4; ++q) {
                const int b = lane * 4 + q;
                hv[q] = vA[(long)b * MST + row];
                kp[q] = b * 16 + (int)iA[(long)b * MST + row];
            }
            double best = -3.0; int bi = 0;
            for (int u = 0; u < 16; ++u) {
                const float* wr = &W2r[(long)(gblk * 16 + u) * 4096];
                double su = hv[0] * (double)wr[kp[0]] + hv[1] * (double)wr[kp[1]]
                          + hv[2] * (double)wr[kp[2]] + hv[3] * (double)wr[kp[3]];
#pragma unroll
                for (int off = 32; off; off >>= 1) su += __shfl_xor(su, off);
                const double xu = fmin(fmax(su + (double)bias[gblk * 16 + u], -1.0), 1.0);
                if (xu > best) { best = xu; bi = u; }
            }
            if (lane == 0) { iFix[s] = (uint8_t)bi; vFix[s] = (float)best; }
        }
    }
}

// ---------------------------------------------------------------------------
extern "C" void kernel_launch(void* const* d_in, const int* in_sizes, int n_in,
                              void* d_out, int out_size, void* d_ws, size_t ws_size,
                              hipStream_t stream)
{
    const float* x    = (const float*)d_in[0];
    const float* W1   = (const float*)d_in[1];
    const float* b1   = (const float*)d_in[2];
    const float* W2   = (const float*)d_in[3];
    const float* b2   = (const float*)d_in[4];
    const float* Wout = (const float*)d_in[5];
    const float* bout = (const float*)d_in[6];
    float* out = (float*)d_out;
    (void)in_sizes; (void)n_in; (void)out_size; (void)ws_size;

    const int B = 8192, Din = 1024, H = 4096, Dout = 1024;

    char* ws = (char*)d_ws;
    double*  v1d = (double*)ws;                       // 16 MB [256][8192]
    float*   v1f = (float*)(ws + (16ll << 20));       //  8 MB
    uint8_t* i1  = (uint8_t*)(ws + (24ll << 20));     //  2 MB
    uint8_t* f1  = (uint8_t*)(ws + (26ll << 20));     //  2 MB
    float*   v2f = (float*)(ws + (28ll << 20));       //  8 MB
    uint8_t* i2  = (uint8_t*)(ws + (36ll << 20));     //  2 MB
    uint8_t* f2  = (uint8_t*)(ws + (38ll << 20));     //  2 MB

    dim3 blk(256);
    k1a_dense_f32_flags<<<dim3(H / 256, B / 128), blk, 0, stream>>>(
        x, W1, b1, Din, i1, f1);
    k1b_winner_f64<<<dim3(H / 128, B / 128), blk, 0, stream>>>(
        x, W1, b1, Din, i1, v1d, v1f);
    k1_resolve<<<1024, blk, 0, stream>>>(x, W1, b1, f1, i1, v1d, v1f);
    sparse_gemm_v3<true><<<dim3(H / 256, B / 64), blk, 0, stream>>>(
        v1f, i1, W2, b2, H, EPS2, v2f, i2, f2, nullptr, H);
    k2_resolve<<<1024, blk, 0, stream>>>(v1d, i1, W2, b2, f2, i2, v2f);
    sparse_gemm_v3<false><<<dim3(Dout / 256, B / 64), blk, 0, stream>>>(
        v2f, i2, Wout, bout, H, 0.f, nullptr, nullptr, nullptr, out, Dout);
}